// Round 3
// baseline (149.326 us; speedup 1.0000x reference)
//
#include <hip/hip_runtime.h>

#define NB 128
#define NS 8192
#define NC 128                // chunks per sequence (64-step chunks; r0-proven geometry)
#define NCP 8                 // combined matrices per sequence (one per block)
#define NL (NS / NC)          // 64 steps per chunk
#define M4 (NL / 4)           // 16 float4 groups

#define LOG2E 1.4426950408889634f
#define HLOG2PI 0.918938533204672742f
#define LN2 0.69314718055994531f

// LDS matrix layout: R-only units (r1-proven). Transposed operand in combine
// is read strided (8-way broadcast float2 reads -> conflict-free). mx scale
// lives in row-0 pad (col 16).
#define ROWS 20          // padded leading dim
#define UNIT 320         // one unit: R[16x20]

__device__ __forceinline__ float fexp2(float x) { return __builtin_amdgcn_exp2f(x); }
__device__ __forceinline__ float flog2(float x) { return __builtin_amdgcn_logf(x); }

__device__ __forceinline__ float gsum16(float v) {
    v += __shfl_xor(v, 1, 16);
    v += __shfl_xor(v, 2, 16);
    v += __shfl_xor(v, 4, 16);
    v += __shfl_xor(v, 8, 16);
    return v;
}
__device__ __forceinline__ float gmax16(float v) {
    v = fmaxf(v, __shfl_xor(v, 1, 16));
    v = fmaxf(v, __shfl_xor(v, 2, 16));
    v = fmaxf(v, __shfl_xor(v, 4, 16));
    v = fmaxf(v, __shfl_xor(v, 8, 16));
    return v;
}

// Fused broadcast-multiply: W *= rot_k(mylg) in ONE VOP2+DPP instruction.
#define MULROT(w, K)                                                            \
    asm("v_mul_f32_dpp %0, %1, %0 row_ror:" #K " row_mask:0xf bank_mask:0xf"    \
        : "+v"(w) : "v"(mylg))

// One HMM step, rotated-W layout, SCALAR form with fused DPP muls.
// W[k] = column entry for row (r+k)&15. Takes colsum T, returns new colsum.
__device__ __forceinline__ float stepS(float (&W)[16], float T, float xx,
                                       float A2, float B2, float C2) {
    const float amb = 0.9f - 0.1f / 15.0f;
    const float bco = 0.1f / 15.0f;
    float myl = fexp2(fmaf(xx, fmaf(xx, A2, B2), C2));   // ONE exp per lane
    float bT = bco * T;
    float mylg;
    asm("v_mov_b32 %0, %1\n\ts_nop 1" : "=v"(mylg) : "v"(myl));
#pragma unroll
    for (int k = 0; k < 16; ++k) W[k] = fmaf(amb, W[k], bT);
    W[0] *= myl;
    MULROT(W[1], 1);   MULROT(W[2], 2);   MULROT(W[3], 3);
    MULROT(W[4], 4);   MULROT(W[5], 5);   MULROT(W[6], 6);
    MULROT(W[7], 7);   MULROT(W[8], 8);   MULROT(W[9], 9);
    MULROT(W[10], 10); MULROT(W[11], 11); MULROT(W[12], 12);
    MULROT(W[13], 13); MULROT(W[14], 14); MULROT(W[15], 15);
    float a0 = W[0] + W[1],   a1 = W[2] + W[3];
    float a2 = W[4] + W[5],   a3 = W[6] + W[7];
    float a4 = W[8] + W[9],   a5 = W[10] + W[11];
    float a6 = W[12] + W[13], a7 = W[14] + W[15];
    float b0 = a0 + a1, b1 = a2 + a3, b2 = a4 + a5, b3 = a6 + a7;
    return (b0 + b1) + (b2 + b3);
}

// Renormalized product of two LDS R-only units: C = Mb * Ma (b = later chunk).
__device__ __forceinline__ void combineUnits(float* lds, int ua, int ub, int ud, int lane) {
    const float* MbR = lds + ub * UNIT;
    const float* MaR = lds + ua * UNIT;
    float mxa = lds[ua * UNIT + 16];
    float mxb = lds[ub * UNIT + 16];
    int a = lane >> 3, cc = lane & 7;
    float b0[16], b1[16];
    const float4* pb0 = (const float4*)(MbR + (2 * a) * ROWS);
    const float4* pb1 = (const float4*)(MbR + (2 * a + 1) * ROWS);
#pragma unroll
    for (int q = 0; q < 4; ++q) {
        *(float4*)&b0[4 * q] = pb0[q];
        *(float4*)&b1[4 * q] = pb1[q];
    }
    float c00 = 0.f, c01 = 0.f, c10 = 0.f, c11 = 0.f;
#pragma unroll
    for (int k = 0; k < 16; ++k) {
        float2 av = *(const float2*)(MaR + k * ROWS + 2 * cc);
        c00 = fmaf(b0[k], av.x, c00);
        c01 = fmaf(b0[k], av.y, c01);
        c10 = fmaf(b1[k], av.x, c10);
        c11 = fmaf(b1[k], av.y, c11);
    }
    float cs0 = c00 + c10;
    float cs1 = c01 + c11;
    cs0 += __shfl_xor(cs0, 8);  cs1 += __shfl_xor(cs1, 8);
    cs0 += __shfl_xor(cs0, 16); cs1 += __shfl_xor(cs1, 16);
    cs0 += __shfl_xor(cs0, 32); cs1 += __shfl_xor(cs1, 32);
    float mxc = fmaxf(cs0, cs1);
    mxc = fmaxf(mxc, __shfl_xor(mxc, 1));
    mxc = fmaxf(mxc, __shfl_xor(mxc, 2));
    mxc = fmaxf(mxc, __shfl_xor(mxc, 4));
    float is = 1.0f / mxc;
    c00 *= is; c01 *= is; c10 *= is; c11 *= is;
    float* dR = lds + ud * UNIT;
    *(float2*)(dR + (2 * a) * ROWS + 2 * cc)     = make_float2(c00, c01);
    *(float2*)(dR + (2 * a + 1) * ROWS + 2 * cc) = make_float2(c10, c11);
    if (lane == 0) lds[ud * UNIT + 16] = mxa + mxb + flog2(mxc);
}

// Phase 1: byte-identical math to R2 (absmax 0.0). See R2 notes.
__global__ __launch_bounds__(256, 4) void hmm_phase1(const float* __restrict__ obvs,
                                                     const float* __restrict__ mu,
                                                     const float* __restrict__ log_sigma,
                                                     float* __restrict__ wsW,
                                                     float* __restrict__ wsM,
                                                     float* __restrict__ out) {
    __shared__ float lds[16 * UNIT];       // 16 R-units, 20,480 B
    int tid = blockIdx.x * 256 + threadIdx.x;
    if (tid == 0) out[0] = 0.0f;           // phase23 atomicAdds after this dispatch
    int r = threadIdx.x & 15;
    int u = threadIdx.x >> 4;              // local chunk 0..15
    int g = tid >> 4;                      // g = b*NC + c
    int b = g >> 7;                        // NC = 128
    int c = g & (NC - 1);

    float ls = log_sigma[r];
    float mk = mu[r];
    float iv = fexp2(-2.0f * LOG2E * ls);
    float A2 = -0.5f * LOG2E * iv;
    float B2 = LOG2E * mk * iv;
    float C2 = LOG2E * (-0.5f * mk * mk * iv - ls - HLOG2PI);

    float W[16];
#pragma unroll
    for (int i = 0; i < 16; ++i) W[i] = 0.0f;
    W[0] = 1.0f;                           // identity in rotated layout
    int ilog = 0;
    float T = 1.0f;

    const float4* ob4 = (const float4*)(obvs + (long)b * NS) + c * M4;
    float4 xv = ob4[0];
    float4 xn = ob4[1];
    // peeled m=0 group: chunk 0 skips t=0 (handled as init vector in phase23)
    if (c) T = stepS(W, T, xv.x, A2, B2, C2);
    T = stepS(W, T, xv.y, A2, B2, C2);
    T = stepS(W, T, xv.z, A2, B2, C2);
    T = stepS(W, T, xv.w, A2, B2, C2);
    {
        int te = (__float_as_int(T) >> 23) & 255;
        int ok = (te != 0);
        float s = ok ? __int_as_float((254 - te) << 23) : 1.0f;
        ilog += ok ? (te - 127) : 0;
#pragma unroll
        for (int i = 0; i < 16; ++i) W[i] *= s;
        T *= s;
    }
    xv = xn;
    for (int m = 1; m < M4; ++m) {
        xn = ob4[(m + 1) < M4 ? (m + 1) : m];
        T = stepS(W, T, xv.x, A2, B2, C2);
        T = stepS(W, T, xv.y, A2, B2, C2);
        T = stepS(W, T, xv.z, A2, B2, C2);
        T = stepS(W, T, xv.w, A2, B2, C2);
        int te = (__float_as_int(T) >> 23) & 255;
        int ok = (te != 0);
        float s = ok ? __int_as_float((254 - te) << 23) : 1.0f;
        ilog += ok ? (te - 127) : 0;
#pragma unroll
        for (int i = 0; i < 16; ++i) W[i] *= s;
        T *= s;
        xv = xn;
    }

    float lg = (float)ilog + flog2(T);     // true column log2-sum (T in [1,2))
    float mx = gmax16(lg);                 // chunk max over 16 columns
    float sc = fexp2((float)ilog - mx);    // scale so chunk max colsum = 1

    float* Ru = lds + u * UNIT;
#pragma unroll
    for (int k = 0; k < 16; ++k) {
        int j = (r + k) & 15;
        Ru[j * ROWS + r] = W[k] * sc;
    }
    if (r == 0) Ru[16] = mx;
    __syncthreads();

    int lane = threadIdx.x & 63;
    int wid = threadIdx.x >> 6;
#pragma unroll
    for (int q = 0; q < 2; ++q) {
        int p = 2 * wid + q;
        combineUnits(lds, 2 * p, 2 * p + 1, 2 * p, lane);
    }
    __syncthreads();
    if (wid < 4) combineUnits(lds, 4 * wid, 4 * wid + 2, 4 * wid, lane);
    __syncthreads();
    if (wid < 2) combineUnits(lds, 8 * wid, 8 * wid + 4, 8 * wid, lane);
    __syncthreads();
    if (wid == 0) combineUnits(lds, 0, 8, 0, lane);
    __syncthreads();

    wsW[(long)blockIdx.x * 256 + threadIdx.x] =
        lds[(threadIdx.x >> 4) * ROWS + (threadIdx.x & 15)];
    if (threadIdx.x == 0) wsM[blockIdx.x] = lds[16];
}

// Phase 2+3: byte-identical to R2.
__global__ __launch_bounds__(256, 2) void hmm_phase23(const float* __restrict__ obvs,
                                                      const float* __restrict__ mu,
                                                      const float* __restrict__ log_sigma,
                                                      const float* __restrict__ prior_logits,
                                                      const float* __restrict__ wsW,
                                                      const float* __restrict__ wsM,
                                                      float* __restrict__ out) {
    __shared__ float lds[16 * UNIT];       // 20,480 B (8 units used)
    int bb = blockIdx.x;
    int tid = threadIdx.x;
    int wid = tid >> 6;
    int lane = tid & 63;

    const float4* src = (const float4*)(wsW + (long)bb * NCP * 256);
#pragma unroll
    for (int q = 0; q < 2; ++q) {
        int f = tid + q * 256;
        float4 v = src[f];
        int m = f >> 6, idx = f & 63, j = idx >> 2, kq = idx & 3;
        *(float4*)(lds + m * UNIT + j * ROWS + kq * 4) = v;
    }
    if (tid < NCP) lds[tid * UNIT + 16] = 0.0f;   // inputs carry no LDS scale
    __syncthreads();

    if (wid < 4) combineUnits(lds, 2 * wid, 2 * wid + 1, 2 * wid, lane);
    __syncthreads();
    if (wid < 2) combineUnits(lds, 4 * wid, 4 * wid + 2, 4 * wid, lane);
    __syncthreads();
    if (wid == 0) combineUnits(lds, 0, 4, 0, lane);
    __syncthreads();

    if (tid < 16) {
        int jj = tid;
        float ls = log_sigma[jj];
        float mk = mu[jj];
        float iv = fexp2(-2.0f * LOG2E * ls);
        float A2 = -0.5f * LOG2E * iv;
        float B2 = LOG2E * mk * iv;
        float C2 = LOG2E * (-0.5f * mk * mk * iv - ls - HLOG2PI);
        float x = obvs[(long)bb * NS];                   // t = 0
        float e = fexp2(LOG2E * prior_logits[jj]);
        float Z = gsum16(e);
        float p0 = fexp2(fmaf(x, fmaf(x, A2, B2), C2)) * e;
        const float* Mrow = lds + jj * ROWS;
        float mr[16];
        *(float4*)&mr[0]  = ((const float4*)Mrow)[0];
        *(float4*)&mr[4]  = ((const float4*)Mrow)[1];
        *(float4*)&mr[8]  = ((const float4*)Mrow)[2];
        *(float4*)&mr[12] = ((const float4*)Mrow)[3];
        float q = 0.0f;
#pragma unroll
        for (int rr = 0; rr < 16; ++rr) q = fmaf(mr[rr], __shfl(p0, rr, 16), q);
        float Tq = gsum16(q);
        float pm = (jj < NCP) ? wsM[bb * NCP + jj] : 0.0f;
        float msum = gsum16(pm);
        if (jj == 0) {
            float res = (flog2(Tq) + lds[16] - flog2(Z) + msum) * LN2;
            atomicAdd(out, res);
        }
    }
}

extern "C" void kernel_launch(void* const* d_in, const int* in_sizes, int n_in,
                              void* d_out, int out_size, void* d_ws, size_t ws_size,
                              hipStream_t stream) {
    const float* obvs = (const float*)d_in[0];
    const float* mu = (const float*)d_in[1];
    const float* log_sigma = (const float*)d_in[2];
    const float* prior_logits = (const float*)d_in[3];
    float* out = (float*)d_out;

    float* wsW = (float*)d_ws;                          // NB*NCP*256 floats = 1.05 MB
    float* wsM = wsW + (size_t)NB * NCP * 256;          // NB*NCP floats

    // ---- MEASUREMENT ROUND (R3) ----
    // phase1 launched 3x total; probes 2+3 write to disjoint scratch at +16MB /
    // +32MB so the real results are untouched. phase1_true = (dur - 92.5us)/2.
    // Probes re-zero out[0] harmlessly (phase23 runs last and accumulates).
    float* wsW2 = (float*)d_ws + (size_t)(4 << 20);     // +16 MB scratch
    float* wsM2 = wsW2 + (size_t)NB * NCP * 256;
    float* wsW3 = (float*)d_ws + (size_t)(8 << 20);     // +32 MB scratch
    float* wsM3 = wsW3 + (size_t)NB * NCP * 256;

    hmm_phase1<<<dim3(NB * NC * 16 / 256), dim3(256), 0, stream>>>(obvs, mu, log_sigma,
                                                                   wsW, wsM, out);
    hmm_phase1<<<dim3(NB * NC * 16 / 256), dim3(256), 0, stream>>>(obvs, mu, log_sigma,
                                                                   wsW2, wsM2, out);
    hmm_phase1<<<dim3(NB * NC * 16 / 256), dim3(256), 0, stream>>>(obvs, mu, log_sigma,
                                                                   wsW3, wsM3, out);
    hmm_phase23<<<dim3(NB), dim3(256), 0, stream>>>(obvs, mu, log_sigma, prior_logits,
                                                    wsW, wsM, out);
}

// Round 4
// 89.064 us; speedup vs baseline: 1.6766x; 1.6766x over previous
//
#include <hip/hip_runtime.h>

#define NB 128
#define NS 8192
#define NC 128                // chunks per sequence (64-step chunks; r0-proven geometry)
#define NCP 8                 // combined matrices per sequence (one per block)
#define NL (NS / NC)          // 64 steps per chunk
#define M4 (NL / 4)           // 16 float4 groups

#define LOG2E 1.4426950408889634f
#define HLOG2PI 0.918938533204672742f
#define LN2 0.69314718055994531f
// amb = 0.9 - 0.1/15 (diagonal coeff), absorbed into log-scale: W~ = W/amb^t.
#define LOG2AMB (-0.16272971f)

// LDS matrix layout: R-only units (r1-proven). Transposed operand in combine
// is read strided (8-way broadcast float2 reads -> conflict-free). mx scale
// lives in row-0 pad (col 16).
#define ROWS 20          // padded leading dim
#define UNIT 320         // one unit: R[16x20]

typedef float v2f __attribute__((ext_vector_type(2)));

__device__ __forceinline__ float fexp2(float x) { return __builtin_amdgcn_exp2f(x); }
__device__ __forceinline__ float flog2(float x) { return __builtin_amdgcn_logf(x); }

__device__ __forceinline__ float gsum16(float v) {
    v += __shfl_xor(v, 1, 16);
    v += __shfl_xor(v, 2, 16);
    v += __shfl_xor(v, 4, 16);
    v += __shfl_xor(v, 8, 16);
    return v;
}
__device__ __forceinline__ float gmax16(float v) {
    v = fmaxf(v, __shfl_xor(v, 1, 16));
    v = fmaxf(v, __shfl_xor(v, 2, 16));
    v = fmaxf(v, __shfl_xor(v, 4, 16));
    v = fmaxf(v, __shfl_xor(v, 8, 16));
    return v;
}

// Fused broadcast-multiply on ONE half of a v2f pair: half *= rot_k(mylg).
// v2f halves are individual VGPRs, so scalar VOP2+DPP on them is free.
// Hazard: mylg comes from the guarded mov (s_nop 1 = 2 wait states, r2-proven).
#define MULROTH(vec, comp, K)                                                       \
    do {                                                                            \
        float _w = vec.comp;                                                        \
        asm("v_mul_f32_dpp %0, %1, %0 row_ror:" #K " row_mask:0xf bank_mask:0xf"    \
            : "+v"(_w) : "v"(mylg));                                                \
        vec.comp = _w;                                                              \
    } while (0)

// One HMM step in RESCALED form (W~ = W/amb^t):
//   W~_new[k] = l_{r+k} * (W~[k] + (bco/amb) * T~)
// The fma degenerates to a pk_add; amb^t is a compile-time log-scale constant
// applied at chunk end. Per-step issue ~84 cy vs 112 for the r2 scalar form:
// 8 v_pk_add (W+U) + 16 v_mul_f32_dpp + 7 v_pk_add colsum + exp + guard.
__device__ __forceinline__ float stepR(v2f (&W)[8], float T, float xx,
                                       float A2, float B2, float C2) {
    const float bcop = (0.1f / 15.0f) / 0.89333333333333333f;   // bco/amb
    float myl = fexp2(fmaf(xx, fmaf(xx, A2, B2), C2));   // ONE exp per lane
    float U = bcop * T;
    float mylg;
    asm("v_mov_b32 %0, %1\n\ts_nop 1" : "=v"(mylg) : "v"(myl));
    v2f U2 = {U, U};
#pragma unroll
    for (int i = 0; i < 8; ++i) W[i] += U2;              // v_pk_add_f32
    { float _w = W[0].x; _w *= myl; W[0].x = _w; }
    MULROTH(W[0], y, 1);
    MULROTH(W[1], x, 2);   MULROTH(W[1], y, 3);
    MULROTH(W[2], x, 4);   MULROTH(W[2], y, 5);
    MULROTH(W[3], x, 6);   MULROTH(W[3], y, 7);
    MULROTH(W[4], x, 8);   MULROTH(W[4], y, 9);
    MULROTH(W[5], x, 10);  MULROTH(W[5], y, 11);
    MULROTH(W[6], x, 12);  MULROTH(W[6], y, 13);
    MULROTH(W[7], x, 14);  MULROTH(W[7], y, 15);
    v2f s = ((W[0] + W[1]) + (W[2] + W[3])) + ((W[4] + W[5]) + (W[6] + W[7]));
    return s.x + s.y;
}

// Renormalized product of two LDS R-only units: C = Mb * Ma (b = later chunk).
__device__ __forceinline__ void combineUnits(float* lds, int ua, int ub, int ud, int lane) {
    const float* MbR = lds + ub * UNIT;
    const float* MaR = lds + ua * UNIT;
    float mxa = lds[ua * UNIT + 16];
    float mxb = lds[ub * UNIT + 16];
    int a = lane >> 3, cc = lane & 7;
    float b0[16], b1[16];
    const float4* pb0 = (const float4*)(MbR + (2 * a) * ROWS);
    const float4* pb1 = (const float4*)(MbR + (2 * a + 1) * ROWS);
#pragma unroll
    for (int q = 0; q < 4; ++q) {
        *(float4*)&b0[4 * q] = pb0[q];
        *(float4*)&b1[4 * q] = pb1[q];
    }
    float c00 = 0.f, c01 = 0.f, c10 = 0.f, c11 = 0.f;
#pragma unroll
    for (int k = 0; k < 16; ++k) {
        float2 av = *(const float2*)(MaR + k * ROWS + 2 * cc);
        c00 = fmaf(b0[k], av.x, c00);
        c01 = fmaf(b0[k], av.y, c01);
        c10 = fmaf(b1[k], av.x, c10);
        c11 = fmaf(b1[k], av.y, c11);
    }
    float cs0 = c00 + c10;
    float cs1 = c01 + c11;
    cs0 += __shfl_xor(cs0, 8);  cs1 += __shfl_xor(cs1, 8);
    cs0 += __shfl_xor(cs0, 16); cs1 += __shfl_xor(cs1, 16);
    cs0 += __shfl_xor(cs0, 32); cs1 += __shfl_xor(cs1, 32);
    float mxc = fmaxf(cs0, cs1);
    mxc = fmaxf(mxc, __shfl_xor(mxc, 1));
    mxc = fmaxf(mxc, __shfl_xor(mxc, 2));
    mxc = fmaxf(mxc, __shfl_xor(mxc, 4));
    float is = 1.0f / mxc;
    c00 *= is; c01 *= is; c10 *= is; c11 *= is;
    float* dR = lds + ud * UNIT;
    *(float2*)(dR + (2 * a) * ROWS + 2 * cc)     = make_float2(c00, c01);
    *(float2*)(dR + (2 * a + 1) * ROWS + 2 * cc) = make_float2(c10, c11);
    if (lane == 0) lds[ud * UNIT + 16] = mxa + mxb + flog2(mxc);
}

// Phase 1: thread (b, chunk c, column r) evolves basis e_r through a 64-step
// chunk in rescaled form; block tree-combines its 16 chunks 16->1 with
// per-level renorm (INVARIANT: every stored/combined matrix is
// max-colsum-normalized). R3 measurement: phase1 ~= 28.4 us; R2-vs-R0 showed
// equal-issue steps time equal -> issue-bound at throttled VALU clock
// (~1.6 GHz per m07's 103/157 TF scalar-fma ceiling). This round cuts step
// issue ~25% via the amb-absorption rescale.
__global__ __launch_bounds__(256, 4) void hmm_phase1(const float* __restrict__ obvs,
                                                     const float* __restrict__ mu,
                                                     const float* __restrict__ log_sigma,
                                                     float* __restrict__ wsW,
                                                     float* __restrict__ wsM,
                                                     float* __restrict__ out) {
    __shared__ float lds[16 * UNIT];       // 16 R-units, 20,480 B
    int tid = blockIdx.x * 256 + threadIdx.x;
    if (tid == 0) out[0] = 0.0f;           // phase23 atomicAdds after this dispatch
    int r = threadIdx.x & 15;
    int u = threadIdx.x >> 4;              // local chunk 0..15
    int g = tid >> 4;                      // g = b*NC + c
    int b = g >> 7;                        // NC = 128
    int c = g & (NC - 1);

    float ls = log_sigma[r];
    float mk = mu[r];
    float iv = fexp2(-2.0f * LOG2E * ls);
    float A2 = -0.5f * LOG2E * iv;
    float B2 = LOG2E * mk * iv;
    float C2 = LOG2E * (-0.5f * mk * mk * iv - ls - HLOG2PI);

    v2f W[8];
#pragma unroll
    for (int i = 0; i < 8; ++i) W[i] = (v2f){0.0f, 0.0f};
    W[0].x = 1.0f;                         // identity in rotated layout
    int ilog = 0;
    float T = 1.0f;

    const float4* ob4 = (const float4*)(obvs + (long)b * NS) + c * M4;
    float4 xv = ob4[0];
    float4 xn = ob4[1];
    // peeled m=0 group: chunk 0 skips t=0 (handled as init vector in phase23)
    if (c) T = stepR(W, T, xv.x, A2, B2, C2);
    T = stepR(W, T, xv.y, A2, B2, C2);
    T = stepR(W, T, xv.z, A2, B2, C2);
    T = stepR(W, T, xv.w, A2, B2, C2);
    {
        int te = (__float_as_int(T) >> 23) & 255;
        int ok = (te != 0);
        float s = ok ? __int_as_float((254 - te) << 23) : 1.0f;
        ilog += ok ? (te - 127) : 0;
        v2f s2 = {s, s};
#pragma unroll
        for (int i = 0; i < 8; ++i) W[i] *= s2;
        T *= s;
    }
    xv = xn;
    for (int m = 1; m < M4; ++m) {
        xn = ob4[(m + 1) < M4 ? (m + 1) : m];
        T = stepR(W, T, xv.x, A2, B2, C2);
        T = stepR(W, T, xv.y, A2, B2, C2);
        T = stepR(W, T, xv.z, A2, B2, C2);
        T = stepR(W, T, xv.w, A2, B2, C2);
        // guarded branchless exponent renorm (proven)
        int te = (__float_as_int(T) >> 23) & 255;
        int ok = (te != 0);
        float s = ok ? __int_as_float((254 - te) << 23) : 1.0f;
        ilog += ok ? (te - 127) : 0;
        v2f s2 = {s, s};
#pragma unroll
        for (int i = 0; i < 8; ++i) W[i] *= s2;
        T *= s;
        xv = xn;
    }

    // true column log2-sum: physical W = amb^t * 2^{ilog} * W~_stored
    float camb = (c ? 64.0f : 63.0f) * LOG2AMB;
    float lg = (float)ilog + camb + flog2(T);   // T in [1,2)
    float mx = gmax16(lg);                      // chunk max over 16 columns
    float sc = fexp2((float)ilog + camb - mx);  // scale so chunk max colsum = 1

    // normalized chunk matrix into LDS R layout; row of W[i].{x,y} is (r+2i(+1))&15
    float* Ru = lds + u * UNIT;
#pragma unroll
    for (int i = 0; i < 8; ++i) {
        int j0 = (r + 2 * i) & 15;
        int j1 = (r + 2 * i + 1) & 15;
        Ru[j0 * ROWS + r] = W[i].x * sc;
        Ru[j1 * ROWS + r] = W[i].y * sc;
    }
    if (r == 0) Ru[16] = mx;
    __syncthreads();

    // in-LDS renormalized tree 16 -> 8 -> 4 -> 2 -> 1 (proven structure)
    int lane = threadIdx.x & 63;
    int wid = threadIdx.x >> 6;
#pragma unroll
    for (int q = 0; q < 2; ++q) {
        int p = 2 * wid + q;
        combineUnits(lds, 2 * p, 2 * p + 1, 2 * p, lane);
    }
    __syncthreads();
    if (wid < 4) combineUnits(lds, 4 * wid, 4 * wid + 2, 4 * wid, lane);
    __syncthreads();
    if (wid < 2) combineUnits(lds, 8 * wid, 8 * wid + 4, 8 * wid, lane);
    __syncthreads();
    if (wid == 0) combineUnits(lds, 0, 8, 0, lane);
    __syncthreads();

    // emit: one matrix per block in [j][r] layout + its log2-scale
    wsW[(long)blockIdx.x * 256 + threadIdx.x] =
        lds[(threadIdx.x >> 4) * ROWS + (threadIdx.x & 15)];
    if (threadIdx.x == 0) wsM[blockIdx.x] = lds[16];
}

// Phase 2+3: stage 8 matrices per sequence, renormalizing 8->1 tree
// (3 renormed levels), then the t=0 init-vector epilogue. Tree log2-scale
// (lds[16]) joins msum.
__global__ __launch_bounds__(256, 2) void hmm_phase23(const float* __restrict__ obvs,
                                                      const float* __restrict__ mu,
                                                      const float* __restrict__ log_sigma,
                                                      const float* __restrict__ prior_logits,
                                                      const float* __restrict__ wsW,
                                                      const float* __restrict__ wsM,
                                                      float* __restrict__ out) {
    __shared__ float lds[16 * UNIT];       // 20,480 B (8 units used)
    int bb = blockIdx.x;
    int tid = threadIdx.x;
    int wid = tid >> 6;
    int lane = tid & 63;

    const float4* src = (const float4*)(wsW + (long)bb * NCP * 256);
#pragma unroll
    for (int q = 0; q < 2; ++q) {
        int f = tid + q * 256;
        float4 v = src[f];
        int m = f >> 6, idx = f & 63, j = idx >> 2, kq = idx & 3;
        *(float4*)(lds + m * UNIT + j * ROWS + kq * 4) = v;
    }
    if (tid < NCP) lds[tid * UNIT + 16] = 0.0f;   // inputs carry no LDS scale
    __syncthreads();

    // tree 8 -> 4 -> 2 -> 1 (later * earlier), renormed at every level
    if (wid < 4) combineUnits(lds, 2 * wid, 2 * wid + 1, 2 * wid, lane);
    __syncthreads();
    if (wid < 2) combineUnits(lds, 4 * wid, 4 * wid + 2, 4 * wid, lane);
    __syncthreads();
    if (wid == 0) combineUnits(lds, 0, 4, 0, lane);
    __syncthreads();
    // final combined matrix rows at lds[j*ROWS + k], tree scale at lds[16]

    if (tid < 16) {
        int jj = tid;
        float ls = log_sigma[jj];
        float mk = mu[jj];
        float iv = fexp2(-2.0f * LOG2E * ls);
        float A2 = -0.5f * LOG2E * iv;
        float B2 = LOG2E * mk * iv;
        float C2 = LOG2E * (-0.5f * mk * mk * iv - ls - HLOG2PI);
        float x = obvs[(long)bb * NS];                   // t = 0
        float e = fexp2(LOG2E * prior_logits[jj]);
        float Z = gsum16(e);
        float p0 = fexp2(fmaf(x, fmaf(x, A2, B2), C2)) * e;
        const float* Mrow = lds + jj * ROWS;
        float mr[16];
        *(float4*)&mr[0]  = ((const float4*)Mrow)[0];
        *(float4*)&mr[4]  = ((const float4*)Mrow)[1];
        *(float4*)&mr[8]  = ((const float4*)Mrow)[2];
        *(float4*)&mr[12] = ((const float4*)Mrow)[3];
        float q = 0.0f;
#pragma unroll
        for (int rr = 0; rr < 16; ++rr) q = fmaf(mr[rr], __shfl(p0, rr, 16), q);
        float Tq = gsum16(q);
        float pm = (jj < NCP) ? wsM[bb * NCP + jj] : 0.0f;
        float msum = gsum16(pm);
        if (jj == 0) {
            float res = (flog2(Tq) + lds[16] - flog2(Z) + msum) * LN2;
            atomicAdd(out, res);
        }
    }
}

extern "C" void kernel_launch(void* const* d_in, const int* in_sizes, int n_in,
                              void* d_out, int out_size, void* d_ws, size_t ws_size,
                              hipStream_t stream) {
    const float* obvs = (const float*)d_in[0];
    const float* mu = (const float*)d_in[1];
    const float* log_sigma = (const float*)d_in[2];
    const float* prior_logits = (const float*)d_in[3];
    float* out = (float*)d_out;

    float* wsW = (float*)d_ws;                          // NB*NCP*256 floats = 1.05 MB
    float* wsM = wsW + (size_t)NB * NCP * 256;          // NB*NCP floats

    hmm_phase1<<<dim3(NB * NC * 16 / 256), dim3(256), 0, stream>>>(obvs, mu, log_sigma,
                                                                   wsW, wsM, out);
    hmm_phase23<<<dim3(NB), dim3(256), 0, stream>>>(obvs, mu, log_sigma, prior_logits,
                                                    wsW, wsM, out);
}